// Round 5
// baseline (141.113 us; speedup 1.0000x reference)
//
#include <hip/hip_runtime.h>

// Problem constants (CARAFE, delta=2, kup=5)
constexpr int N_  = 4;
constexpr int C_  = 256;
constexpr int H_  = 64;
constexpr int W_  = 64;
constexpr int Cm_ = 64;
constexpr int ENC = 100;
constexpr int OC_ = 256;
constexpr int HW_ = H_ * W_;       // 4096
constexpr int H2_ = 128, W2_ = 128;

typedef float  f32x16 __attribute__((ext_vector_type(16)));
typedef float  f32x4  __attribute__((ext_vector_type(4)));
typedef float  f32x2  __attribute__((ext_vector_type(2)));
typedef short  s16x8  __attribute__((ext_vector_type(8)));

__device__ inline unsigned short f2bf(float f) {
    unsigned int u = __float_as_uint(f);
    unsigned int r = u + 0x7FFFu + ((u >> 16) & 1u);  // RNE
    return (unsigned short)(r >> 16);
}
// packed f32 pair -> bf16x2 dword (lo = a, hi = b), RNE
__device__ inline unsigned int cvt_pk_bf16(float a, float b) {
    unsigned int r;
    asm volatile("v_cvt_pk_bf16_f32 %0, %1, %2" : "=v"(r) : "v"(a), "v"(b));
    return r;
}
// unpack 2 consecutive bf16 (little-endian dword) -> f32x2
__device__ inline f32x2 bfp2f(unsigned int u) {
    f32x2 r;
    r.x = __uint_as_float(u << 16);
    r.y = __uint_as_float(u & 0xffff0000u);
    return r;
}
// d.lo += a.lo*b.lo ; d.hi += a.hi*b.lo   (broadcast low half of b)
__device__ inline void pk_fma_lo(f32x2& d, f32x2 a, f32x2 b) {
    asm volatile("v_pk_fma_f32 %0, %1, %2, %0 op_sel:[0,0,0] op_sel_hi:[1,0,1]"
                 : "+v"(d) : "v"(a), "v"(b));
}
// d.lo += a.lo*b.hi ; d.hi += a.hi*b.hi   (broadcast high half of b)
__device__ inline void pk_fma_hi(f32x2& d, f32x2 a, f32x2 b) {
    asm volatile("v_pk_fma_f32 %0, %1, %2, %0 op_sel:[0,1,0] op_sel_hi:[1,1,1]"
                 : "+v"(d) : "v"(a), "v"(b));
}

// ---------------- K1: fused {y1 = Wo.x} and {t = Wd.x + bd} via MFMA
// v4: k_prep folded away. Main blocks (b<512) convert Wo/Wd fragments
// on-the-fly (fp32 float4 loads + v_cvt_pk_bf16_f32, double-buffered);
// tail blocks (b>=512) transpose We -> Web (needed only by k_encsm, which
// waits on this kernel anyway). Weight preload issued before x staging.
__global__ __launch_bounds__(640) void k_gemm(const float* __restrict__ x,
                                              const float* __restrict__ Wo,
                                              const float* __restrict__ Wd,
                                              const float* __restrict__ bd,
                                              const float* __restrict__ We,
                                              unsigned short* __restrict__ y1b,
                                              unsigned short* __restrict__ t2,
                                              unsigned short* __restrict__ Web) {
    int b   = blockIdx.x;
    int tid = threadIdx.x;

    if (b >= 512) {                    // ---- Web prep tail: We (o,m,tap) -> [tap][128][64]
        int idx = (b - 512) * 640 + tid;          // 73728 elems over 116 blocks
        if (idx < 73728) {
            int tap = idx >> 13;
            int rem = idx & 8191;
            int o   = rem >> 6;
            int m   = rem & 63;
            Web[idx] = (o < ENC) ? f2bf(We[(o * Cm_ + m) * 9 + tap]) : (unsigned short)0;
        }
        return;
    }

    int wh  = b & 1;                   // 2 wh * 64 h * 4 n = 512
    int h   = (b >> 1) & 63;
    int n   = b >> 7;
    int lane = tid & 63;
    int wv   = tid >> 6;               // 0..9 = o-tile

    int oL   = lane & 31;
    int half = lane >> 5;

    // weight fragment source (fp32, L2-resident after first blocks)
    const float* wrow = (wv < 8) ? Wo + ((size_t)(wv * 32 + oL)) * C_
                                 : Wd + ((size_t)((wv - 8) * 32 + oL)) * C_;
    const float* wpf  = wrow + half * 8;

    float4 w32[2][2];
    w32[0][0] = *(const float4*)&wpf[0];       // issue early: hides under x staging
    w32[0][1] = *(const float4*)&wpf[4];

    __shared__ unsigned short xs[32 * 260];   // 16,640 B: [pix 0..31][c 0..255] (+pad)
    __shared__ unsigned short tbuf[32 * 72];  //  4,608 B: [pix][m] for t2 transpose

    // stage x tile (32 pixels x 256 channels), packed bf16x2 writes
    {
        unsigned int* xd = (unsigned int*)xs;     // row stride 130 dwords
        for (int idx = tid; idx < 1024; idx += 640) {
            int c2  = idx >> 3;                   // channel pair 0..127
            int pg4 = idx & 7;                    // pixel quad 0..7
            const float* xc = x + (size_t)n * C_ * HW_ + (size_t)(c2 * 2) * HW_
                                + h * 64 + wh * 32 + pg4 * 4;
            float4 a  = *(const float4*)xc;
            float4 bq = *(const float4*)(xc + HW_);
            int base = (pg4 * 4) * 130 + c2;
            xd[base]       = cvt_pk_bf16(a.x, bq.x);
            xd[base + 130] = cvt_pk_bf16(a.y, bq.y);
            xd[base + 260] = cvt_pk_bf16(a.z, bq.z);
            xd[base + 390] = cvt_pk_bf16(a.w, bq.w);
        }
    }
    __syncthreads();

    f32x16 acc;
#pragma unroll
    for (int i = 0; i < 16; i++) acc[i] = 0.f;

    const unsigned short* tb = &xs[(lane & 31) * 260 + half * 8];

    for (int kc = 0; kc < 16; kc++) {
        int cur = kc & 1;
        if (kc < 15) {
            w32[cur ^ 1][0] = *(const float4*)&wpf[(kc + 1) * 16];
            w32[cur ^ 1][1] = *(const float4*)&wpf[(kc + 1) * 16 + 4];
        }
        s16x8 wf;
        unsigned int* wfd = (unsigned int*)&wf;
        wfd[0] = cvt_pk_bf16(w32[cur][0].x, w32[cur][0].y);
        wfd[1] = cvt_pk_bf16(w32[cur][0].z, w32[cur][0].w);
        wfd[2] = cvt_pk_bf16(w32[cur][1].x, w32[cur][1].y);
        wfd[3] = cvt_pk_bf16(w32[cur][1].z, w32[cur][1].w);
        s16x8 bfv;
        ((uint2*)&bfv)[0] = *(const uint2*)&tb[kc * 16];
        ((uint2*)&bfv)[1] = *(const uint2*)&tb[kc * 16 + 4];
        acc = __builtin_amdgcn_mfma_f32_32x32x16_bf16(wf, bfv, acc, 0, 0, 0);
    }

    int col = lane & 31;
    int pix = h * 64 + wh * 32 + col;

    // t-waves: deposit transposed tile into LDS first
    if (wv >= 8) {
#pragma unroll
        for (int r = 0; r < 16; r += 2) {
            int m = (wv - 8) * 32 + (r & 3) + 8 * (r >> 2) + 4 * half;   // even
            float2 bdv = *(const float2*)&bd[m];
            *(unsigned int*)&tbuf[col * 72 + m] = cvt_pk_bf16(acc[r] + bdv.x, acc[r + 1] + bdv.y);
        }
    }
    __syncthreads();

    if (wv < 8) {
#pragma unroll
        for (int r = 0; r < 16; r++) {
            int o = wv * 32 + (r & 3) + 8 * (r >> 2) + 4 * half;
            y1b[((size_t)(n * OC_ + o)) * HW_ + pix] = f2bf(acc[r]);
        }
    } else {
        // coalesced t2 store: 128 threads, 4 per 128B pixel-row
        int idx = tid - 512;            // 0..127
        int row = idx >> 2;             // pixel 0..31
        int p   = idx & 3;              // 32B chunk
        const uint4* src = (const uint4*)&tbuf[row * 72 + p * 16];
        uint4 v0 = src[0];
        uint4 v1 = src[1];
        uint4* dst = (uint4*)(t2 + ((size_t)(n * HW_ + h * 64 + wh * 32 + row)) * 64 + p * 16);
        dst[0] = v0;
        dst[1] = v1;
    }
}

// ---------------- K2: fused 3x3 encoder conv (MFMA) + softmax -> kern2 fp32
// v3: tap-0 weight preload issued before t2 staging (hides global latency
// under the staging loop instead of serializing after the barrier).
// kern2 layout: [n][h][k][w][ij] fp32
__global__ __launch_bounds__(256) void k_encsm(const unsigned short* __restrict__ t2,
                                               const unsigned short* __restrict__ Web,
                                               const float* __restrict__ be,
                                               float* __restrict__ kern2) {
    int b    = blockIdx.x;             // 2 ph * 64 h * 4 n = 512
    int ph   = b & 1;
    int h    = (b >> 1) & 63;
    int n    = b >> 7;
    int pix0 = ph * 32;
    int tid  = threadIdx.x;
    int lane = tid & 63;
    int wv   = tid >> 6;
    int o0   = wv * 32;

    __shared__ unsigned short ts[3 * 34 * 68];   // 13,872 B
    __shared__ float          es[32 * 105];      // 13,440 B

    int oL   = lane & 31;
    int half = lane >> 5;
    const unsigned short* wb = Web + ((size_t)(o0 + oL)) * 64 + half * 8;

    s16x8 wf[2][4];
#pragma unroll
    for (int kc = 0; kc < 4; kc++)               // issue before staging
        *(uint4*)&wf[0][kc] = *(const uint4*)&wb[kc * 16];

    for (int idx = tid; idx < 3 * 34 * 8; idx += 256) {
        int r   = idx / 272;
        int rem = idx - r * 272;
        int cw  = rem >> 3;
        int mc  = rem & 7;
        int gh  = h - 1 + r;
        int gw  = pix0 + cw - 1;
        uint2 lo = make_uint2(0u, 0u), hi = make_uint2(0u, 0u);
        if (gh >= 0 && gh < H_ && gw >= 0 && gw < W_) {
            uint4 v = *(const uint4*)&t2[((size_t)(n * HW_ + gh * W_ + gw)) * 64 + mc * 8];
            lo = make_uint2(v.x, v.y); hi = make_uint2(v.z, v.w);
        }
        int la = (r * 34 + cw) * 68 + mc * 8;
        *(uint2*)&ts[la]     = lo;
        *(uint2*)&ts[la + 4] = hi;
    }
    __syncthreads();

    f32x16 acc0, acc1;
#pragma unroll
    for (int i = 0; i < 16; i++) { acc0[i] = 0.f; acc1[i] = 0.f; }

    for (int tap = 0; tap < 9; tap++) {
        int cur = tap & 1;
        if (tap < 8) {
            const unsigned short* wn = wb + (size_t)(tap + 1) * 128 * 64;
#pragma unroll
            for (int kc = 0; kc < 4; kc++)
                *(uint4*)&wf[cur ^ 1][kc] = *(const uint4*)&wn[kc * 16];
        }
        int di = tap / 3, dj = tap % 3;
        int cw = (lane & 31) + dj;
        const unsigned short* tb = &ts[(di * 34 + cw) * 68 + half * 8];
#pragma unroll
        for (int kc = 0; kc < 4; kc++) {
            s16x8 bfv;
            ((uint2*)&bfv)[0] = *(const uint2*)&tb[kc * 16];
            ((uint2*)&bfv)[1] = *(const uint2*)&tb[kc * 16 + 4];
            if (kc & 1)
                acc1 = __builtin_amdgcn_mfma_f32_32x32x16_bf16(wf[cur][kc], bfv, acc1, 0, 0, 0);
            else
                acc0 = __builtin_amdgcn_mfma_f32_32x32x16_bf16(wf[cur][kc], bfv, acc0, 0, 0, 0);
        }
    }
#pragma unroll
    for (int i = 0; i < 16; i++) acc0[i] += acc1[i];

    int pixl = lane & 31;
#pragma unroll
    for (int r = 0; r < 16; r++) {
        int o = o0 + (r & 3) + 8 * (r >> 2) + 4 * half;
        if (o < ENC)
            es[pixl * 105 + o] = acc0[r] + be[o];
    }
    __syncthreads();

    if (tid < 128) {
        int pix = tid & 31;
        int ij  = tid >> 5;
        float v[25];
        float mx = -1e30f;
#pragma unroll
        for (int k = 0; k < 25; k++) {
            v[k] = es[pix * 105 + k * 4 + ij];
            mx   = fmaxf(mx, v[k]);
        }
        float s = 0.f;
#pragma unroll
        for (int k = 0; k < 25; k++) {
            v[k] = __expf(v[k] - mx);
            s += v[k];
        }
        float inv = 1.0f / s;
        float* kp = kern2 + (size_t)(n * 64 + h) * 6400 + (size_t)(pix0 + pix) * 4 + ij;
#pragma unroll
        for (int k = 0; k < 25; k++) kp[k * 256] = v[k] * inv;
    }
}

// ---------------- K3: reassembly + pixel shuffle + bias
// h-fastest block decode -> the 8 og-blocks sharing one kern2 row and one
// y1b halo differ by 64 in blockIdx (64%8==0) -> same XCD L2 (default b%8 map).
__global__ __launch_bounds__(256) void k_reasm(const unsigned short* __restrict__ y1b,
                                               const float* __restrict__ kern2,
                                               const float* __restrict__ bo,
                                               float* __restrict__ out) {
    int b  = blockIdx.x;           // 4 n * 8 og * 64 h = 2048, h fastest
    int h  = b & 63;
    int og = (b >> 6) & 7;
    int n  = b >> 9;
    int o0 = og * 32;
    int tid = threadIdx.x;
    int wp  = tid & 31;            // w0 = 2*wp
    int ol  = tid >> 5;            // 8 groups of 4 o

    __shared__ float ks[25 * 256 + 8];   // 25.6 KB: [k][w(swizzled 16B slots)][ij]

    // stage kern row (n,h): 6400 floats, coalesced float4 copy, swizzled slots
    {
        const float4* src = (const float4*)(kern2 + (size_t)(n * 64 + h) * 6400);
        float4* dst = (float4*)ks;
#pragma unroll
        for (int i = 0; i < 7; i++) {
            int idx = tid + i * 256;
            if (idx < 1600) {
                int k = idx >> 6, j = idx & 63;
                dst[(k << 6) + (j ^ ((j >> 3) & 1))] = src[idx];
            }
        }
    }

    // y halo as packed bf16: 4 o x 5 rows x 3 dwords (cols 2wp-2 .. 2wp+3)
    unsigned int yraw[4][5][3];
    {
        const unsigned short* yb = y1b + ((size_t)(n * OC_ + o0 + ol * 4)) * HW_ + (2 * wp - 2);
#pragma unroll
        for (int o = 0; o < 4; o++) {
#pragma unroll
            for (int di = 0; di < 5; di++) {
                int gh  = h - 2 + di;
                int ghc = gh < 0 ? 0 : (gh > H_ - 1 ? H_ - 1 : gh);
                bool rok = (gh >= 0) && (gh < H_);
                const unsigned short* yr = yb + (size_t)o * HW_ + ghc * W_;
                yraw[o][di][0] = (rok && wp > 0)  ? *(const unsigned int*)(yr)     : 0u;
                yraw[o][di][1] =  rok             ? *(const unsigned int*)(yr + 2) : 0u;
                yraw[o][di][2] = (rok && wp < 31) ? *(const unsigned int*)(yr + 4) : 0u;
            }
        }
    }
    __syncthreads();

    f32x2 acc[4][2][2];            // [o][ww][ij-pair]
#pragma unroll
    for (int o = 0; o < 4; o++)
#pragma unroll
        for (int w = 0; w < 2; w++)
#pragma unroll
            for (int p = 0; p < 2; p++) acc[o][w][p] = (f32x2)(0.f);

    const char* kb  = (const char*)ks + wp * 32;
    const int   fsw = (wp >> 2) & 1;     // swizzle: swap 16B halves when wp bit2 set
#pragma unroll
    for (int di = 0; di < 5; di++) {
        f32x2 yv[4][3];
#pragma unroll
        for (int o = 0; o < 4; o++)
#pragma unroll
            for (int q = 0; q < 3; q++)
                yv[o][q] = bfp2f(yraw[o][di][q]);
#pragma unroll
        for (int dj = 0; dj < 5; dj++) {
            const int k = di * 5 + dj;
            union { f32x4 v; f32x2 h2[2]; } kw0, kw1;
            kw0.v = *(const f32x4*)(kb + k * 1024 + (fsw << 4));        // kern[k][w0][ij0..3]
            kw1.v = *(const f32x4*)(kb + k * 1024 + 16 - (fsw << 4));   // kern[k][w1][ij0..3]
#pragma unroll
            for (int o = 0; o < 4; o++) {
                f32x2 pa = yv[o][dj >> 1];
                f32x2 pb = yv[o][(dj + 1) >> 1];
                if (dj & 1) {
                    pk_fma_hi(acc[o][0][0], kw0.h2[0], pa);
                    pk_fma_hi(acc[o][0][1], kw0.h2[1], pa);
                    pk_fma_lo(acc[o][1][0], kw1.h2[0], pb);
                    pk_fma_lo(acc[o][1][1], kw1.h2[1], pb);
                } else {
                    pk_fma_lo(acc[o][0][0], kw0.h2[0], pa);
                    pk_fma_lo(acc[o][0][1], kw0.h2[1], pa);
                    pk_fma_hi(acc[o][1][0], kw1.h2[0], pb);
                    pk_fma_hi(acc[o][1][1], kw1.h2[1], pb);
                }
            }
        }
    }

#pragma unroll
    for (int o = 0; o < 4; o++) {
        int oo = o0 + ol * 4 + o;
        float bias = bo[oo];
        float* op = out + (((size_t)(n * OC_ + oo)) * H2_ + 2 * h) * W2_ + 4 * wp;
        float4 r0 = make_float4(acc[o][0][0].x + bias, acc[o][0][0].y + bias,
                                acc[o][1][0].x + bias, acc[o][1][0].y + bias);
        float4 r1 = make_float4(acc[o][0][1].x + bias, acc[o][0][1].y + bias,
                                acc[o][1][1].x + bias, acc[o][1][1].y + bias);
        *(float4*)op         = r0;
        *(float4*)(op + W2_) = r1;
    }
}

extern "C" void kernel_launch(void* const* d_in, const int* in_sizes, int n_in,
                              void* d_out, int out_size, void* d_ws, size_t ws_size,
                              hipStream_t stream) {
    const float* x  = (const float*)d_in[0];
    const float* Wd = (const float*)d_in[1];
    const float* bd = (const float*)d_in[2];
    const float* We = (const float*)d_in[3];
    const float* be = (const float*)d_in[4];
    const float* Wo = (const float*)d_in[5];
    const float* bo = (const float*)d_in[6];
    float* out = (float*)d_out;

    // workspace (bytes), total 17,186,816:
    //   y1b   [0,          8,388,608)   bf16 4x256x4096
    //   kern2 [8,388,608,  14,942,208)  fp32 4x64x25x64x4  (layout [n][h][k][w][ij])
    //   t2    [14,942,208, 17,039,360)  bf16 4x4096x64
    //   Web   [17,039,360, 17,186,816)  bf16 9x128x64
    char* wsb = (char*)d_ws;
    unsigned short* y1b  = (unsigned short*)wsb;
    float*          kern2= (float*)(wsb + 8388608);
    unsigned short* t2   = (unsigned short*)(wsb + 14942208);
    unsigned short* Web  = (unsigned short*)(wsb + 17039360);

    k_gemm  <<<628,  640, 0, stream>>>(x, Wo, Wd, bd, We, y1b, t2, Web);
    k_encsm <<<512,  256, 0, stream>>>(t2, Web, be, kern2);
    k_reasm <<<2048, 256, 0, stream>>>(y1b, kern2, bo, out);
}

// Round 6
// 135.589 us; speedup vs baseline: 1.0407x; 1.0407x over previous
//
#include <hip/hip_runtime.h>

// Problem constants (CARAFE, delta=2, kup=5)
constexpr int N_  = 4;
constexpr int C_  = 256;
constexpr int H_  = 64;
constexpr int W_  = 64;
constexpr int Cm_ = 64;
constexpr int ENC = 100;
constexpr int OC_ = 256;
constexpr int HW_ = H_ * W_;       // 4096
constexpr int H2_ = 128, W2_ = 128;

typedef float  f32x16 __attribute__((ext_vector_type(16)));
typedef float  f32x4  __attribute__((ext_vector_type(4)));
typedef float  f32x2  __attribute__((ext_vector_type(2)));
typedef short  s16x8  __attribute__((ext_vector_type(8)));

__device__ inline unsigned short f2bf(float f) {
    unsigned int u = __float_as_uint(f);
    unsigned int r = u + 0x7FFFu + ((u >> 16) & 1u);  // RNE
    return (unsigned short)(r >> 16);
}
// packed f32 pair -> bf16x2 dword (lo = a, hi = b), RNE
__device__ inline unsigned int cvt_pk_bf16(float a, float b) {
    unsigned int r;
    asm volatile("v_cvt_pk_bf16_f32 %0, %1, %2" : "=v"(r) : "v"(a), "v"(b));
    return r;
}
// unpack 2 consecutive bf16 (little-endian dword) -> f32x2
__device__ inline f32x2 bfp2f(unsigned int u) {
    f32x2 r;
    r.x = __uint_as_float(u << 16);
    r.y = __uint_as_float(u & 0xffff0000u);
    return r;
}
// d.lo += a.lo*b.lo ; d.hi += a.hi*b.lo   (broadcast low half of b)
__device__ inline void pk_fma_lo(f32x2& d, f32x2 a, f32x2 b) {
    asm volatile("v_pk_fma_f32 %0, %1, %2, %0 op_sel:[0,0,0] op_sel_hi:[1,0,1]"
                 : "+v"(d) : "v"(a), "v"(b));
}
// d.lo += a.lo*b.hi ; d.hi += a.hi*b.hi   (broadcast high half of b)
__device__ inline void pk_fma_hi(f32x2& d, f32x2 a, f32x2 b) {
    asm volatile("v_pk_fma_f32 %0, %1, %2, %0 op_sel:[0,1,0] op_sel_hi:[1,1,1]"
                 : "+v"(d) : "v"(a), "v"(b));
}

// ---------------- prep (merged): Wcat = [Wo;Wd] bf16 [320][256]  +  Web bf16 [9][128][64]
__global__ __launch_bounds__(256) void k_prep(const float* __restrict__ Wo,
                                              const float* __restrict__ Wd,
                                              const float* __restrict__ We,
                                              unsigned short* __restrict__ Wcat,
                                              unsigned short* __restrict__ Web) {
    int bb  = blockIdx.x;
    int tid = threadIdx.x;
    if (bb < 320) {
        int idx = bb * 256 + tid;                 // 81920
        int row = idx >> 8, c = idx & 255;
        float v = (row < 256) ? Wo[idx] : Wd[(row - 256) * 256 + c];
        Wcat[idx] = f2bf(v);
    } else {
        int idx = (bb - 320) * 256 + tid;         // 73728
        int tap = idx >> 13;
        int rem = idx & 8191;
        int o   = rem >> 6;
        int m   = rem & 63;
        Web[idx] = (o < ENC) ? f2bf(We[(o * Cm_ + m) * 9 + tap]) : (unsigned short)0;
    }
}

// ---------------- K1: fused {y1 = Wo.x} and {t = Wd.x + bd} via MFMA
// v3: t2 epilogue transposed through LDS -> coalesced 128B dwordx4 stores
// (was 4B-at-128B-stride scalar-transaction pattern).
__global__ __launch_bounds__(640) void k_gemm(const float* __restrict__ x,
                                              const unsigned short* __restrict__ Wcat,
                                              const float* __restrict__ bd,
                                              unsigned short* __restrict__ y1b,
                                              unsigned short* __restrict__ t2) {
    int b   = blockIdx.x;              // 2 wh * 64 h * 4 n = 512
    int wh  = b & 1;
    int h   = (b >> 1) & 63;
    int n   = b >> 7;
    int tid  = threadIdx.x;
    int lane = tid & 63;
    int wv   = tid >> 6;               // 0..9 = o-tile

    __shared__ unsigned short xs[32 * 260];   // 16,640 B: [pix 0..31][c 0..255] (+pad)
    __shared__ unsigned short tbuf[32 * 72];  //  4,608 B: [pix][m] for t2 transpose

    // stage x tile (32 pixels x 256 channels), packed bf16x2 writes
    {
        unsigned int* xd = (unsigned int*)xs;     // row stride 130 dwords
        for (int idx = tid; idx < 1024; idx += 640) {
            int c2  = idx >> 3;                   // channel pair 0..127
            int pg4 = idx & 7;                    // pixel quad 0..7
            const float* xc = x + (size_t)n * C_ * HW_ + (size_t)(c2 * 2) * HW_
                                + h * 64 + wh * 32 + pg4 * 4;
            float4 a  = *(const float4*)xc;
            float4 bq = *(const float4*)(xc + HW_);
            int base = (pg4 * 4) * 130 + c2;
            xd[base]       = cvt_pk_bf16(a.x, bq.x);
            xd[base + 130] = cvt_pk_bf16(a.y, bq.y);
            xd[base + 260] = cvt_pk_bf16(a.z, bq.z);
            xd[base + 390] = cvt_pk_bf16(a.w, bq.w);
        }
    }
    __syncthreads();

    f32x16 acc;
#pragma unroll
    for (int i = 0; i < 16; i++) acc[i] = 0.f;

    int oL   = lane & 31;
    int half = lane >> 5;
    const unsigned short* wb = Wcat + ((size_t)(wv * 32 + oL)) * C_ + half * 8;
    const unsigned short* tb = &xs[(lane & 31) * 260 + half * 8];

    s16x8 wf[2];
    *(uint4*)&wf[0] = *(const uint4*)&wb[0];
    for (int kc = 0; kc < 16; kc++) {
        int cur = kc & 1;
        if (kc < 15)
            *(uint4*)&wf[cur ^ 1] = *(const uint4*)&wb[(kc + 1) * 16];
        s16x8 bfv;
        ((uint2*)&bfv)[0] = *(const uint2*)&tb[kc * 16];
        ((uint2*)&bfv)[1] = *(const uint2*)&tb[kc * 16 + 4];
        acc = __builtin_amdgcn_mfma_f32_32x32x16_bf16(wf[cur], bfv, acc, 0, 0, 0);
    }

    int col = lane & 31;
    int pix = h * 64 + wh * 32 + col;

    // t-waves: deposit transposed tile into LDS first
    if (wv >= 8) {
#pragma unroll
        for (int r = 0; r < 16; r += 2) {
            int m = (wv - 8) * 32 + (r & 3) + 8 * (r >> 2) + 4 * half;   // even
            float2 bdv = *(const float2*)&bd[m];
            *(unsigned int*)&tbuf[col * 72 + m] = cvt_pk_bf16(acc[r] + bdv.x, acc[r + 1] + bdv.y);
        }
    }
    __syncthreads();

    if (wv < 8) {
#pragma unroll
        for (int r = 0; r < 16; r++) {
            int o = wv * 32 + (r & 3) + 8 * (r >> 2) + 4 * half;
            y1b[((size_t)(n * OC_ + o)) * HW_ + pix] = f2bf(acc[r]);
        }
    } else {
        // coalesced t2 store: 128 threads, 4 per 128B pixel-row
        int idx = tid - 512;            // 0..127
        int row = idx >> 2;             // pixel 0..31
        int p   = idx & 3;              // 32B chunk
        const uint4* src = (const uint4*)&tbuf[row * 72 + p * 16];
        uint4 v0 = src[0];
        uint4 v1 = src[1];
        uint4* dst = (uint4*)(t2 + ((size_t)(n * HW_ + h * 64 + wh * 32 + row)) * 64 + p * 16);
        dst[0] = v0;
        dst[1] = v1;
    }
}

// ---------------- K2: fused 3x3 encoder conv (MFMA) + softmax -> kern2 fp32
// v2: accumulator split into two chains (kc parity) -> halved MFMA dep chain
// (grid gives only 2 waves/SIMD; TLP alone can't hide ~18cyc MFMA latency).
// kern2 layout: [n][h][k][w][ij] fp32
__global__ __launch_bounds__(256) void k_encsm(const unsigned short* __restrict__ t2,
                                               const unsigned short* __restrict__ Web,
                                               const float* __restrict__ be,
                                               float* __restrict__ kern2) {
    int b    = blockIdx.x;             // 2 ph * 64 h * 4 n = 512
    int ph   = b & 1;
    int h    = (b >> 1) & 63;
    int n    = b >> 7;
    int pix0 = ph * 32;
    int tid  = threadIdx.x;
    int lane = tid & 63;
    int wv   = tid >> 6;
    int o0   = wv * 32;

    __shared__ unsigned short ts[3 * 34 * 68];   // 13,872 B
    __shared__ float          es[32 * 105];      // 13,440 B

    for (int idx = tid; idx < 3 * 34 * 8; idx += 256) {
        int r   = idx / 272;
        int rem = idx - r * 272;
        int cw  = rem >> 3;
        int mc  = rem & 7;
        int gh  = h - 1 + r;
        int gw  = pix0 + cw - 1;
        uint2 lo = make_uint2(0u, 0u), hi = make_uint2(0u, 0u);
        if (gh >= 0 && gh < H_ && gw >= 0 && gw < W_) {
            uint4 v = *(const uint4*)&t2[((size_t)(n * HW_ + gh * W_ + gw)) * 64 + mc * 8];
            lo = make_uint2(v.x, v.y); hi = make_uint2(v.z, v.w);
        }
        int la = (r * 34 + cw) * 68 + mc * 8;
        *(uint2*)&ts[la]     = lo;
        *(uint2*)&ts[la + 4] = hi;
    }
    __syncthreads();

    f32x16 acc0, acc1;
#pragma unroll
    for (int i = 0; i < 16; i++) { acc0[i] = 0.f; acc1[i] = 0.f; }

    int oL   = lane & 31;
    int half = lane >> 5;
    const unsigned short* wb = Web + ((size_t)(o0 + oL)) * 64 + half * 8;

    s16x8 wf[2][4];
#pragma unroll
    for (int kc = 0; kc < 4; kc++)
        *(uint4*)&wf[0][kc] = *(const uint4*)&wb[kc * 16];

    for (int tap = 0; tap < 9; tap++) {
        int cur = tap & 1;
        if (tap < 8) {
            const unsigned short* wn = wb + (size_t)(tap + 1) * 128 * 64;
#pragma unroll
            for (int kc = 0; kc < 4; kc++)
                *(uint4*)&wf[cur ^ 1][kc] = *(const uint4*)&wn[kc * 16];
        }
        int di = tap / 3, dj = tap % 3;
        int cw = (lane & 31) + dj;
        const unsigned short* tb = &ts[(di * 34 + cw) * 68 + half * 8];
#pragma unroll
        for (int kc = 0; kc < 4; kc++) {
            s16x8 bfv;
            ((uint2*)&bfv)[0] = *(const uint2*)&tb[kc * 16];
            ((uint2*)&bfv)[1] = *(const uint2*)&tb[kc * 16 + 4];
            if (kc & 1)
                acc1 = __builtin_amdgcn_mfma_f32_32x32x16_bf16(wf[cur][kc], bfv, acc1, 0, 0, 0);
            else
                acc0 = __builtin_amdgcn_mfma_f32_32x32x16_bf16(wf[cur][kc], bfv, acc0, 0, 0, 0);
        }
    }
#pragma unroll
    for (int i = 0; i < 16; i++) acc0[i] += acc1[i];

    int pixl = lane & 31;
#pragma unroll
    for (int r = 0; r < 16; r++) {
        int o = o0 + (r & 3) + 8 * (r >> 2) + 4 * half;
        if (o < ENC)
            es[pixl * 105 + o] = acc0[r] + be[o];
    }
    __syncthreads();

    if (tid < 128) {
        int pix = tid & 31;
        int ij  = tid >> 5;
        float v[25];
        float mx = -1e30f;
#pragma unroll
        for (int k = 0; k < 25; k++) {
            v[k] = es[pix * 105 + k * 4 + ij];
            mx   = fmaxf(mx, v[k]);
        }
        float s = 0.f;
#pragma unroll
        for (int k = 0; k < 25; k++) {
            v[k] = __expf(v[k] - mx);
            s += v[k];
        }
        float inv = 1.0f / s;
        float* kp = kern2 + (size_t)(n * 64 + h) * 6400 + (size_t)(pix0 + pix) * 4 + ij;
#pragma unroll
        for (int k = 0; k < 25; k++) kp[k * 256] = v[k] * inv;
    }
}

// ---------------- K3: reassembly + pixel shuffle + bias
// v4: h-fastest block decode -> the 8 og-blocks sharing one kern2 row and one
// y1b halo differ by 64 in blockIdx (64%8==0) -> same XCD L2 (default b%8 map).
__global__ __launch_bounds__(256) void k_reasm(const unsigned short* __restrict__ y1b,
                                               const float* __restrict__ kern2,
                                               const float* __restrict__ bo,
                                               float* __restrict__ out) {
    int b  = blockIdx.x;           // 4 n * 8 og * 64 h = 2048, h fastest
    int h  = b & 63;
    int og = (b >> 6) & 7;
    int n  = b >> 9;
    int o0 = og * 32;
    int tid = threadIdx.x;
    int wp  = tid & 31;            // w0 = 2*wp
    int ol  = tid >> 5;            // 8 groups of 4 o

    __shared__ float ks[25 * 256 + 8];   // 25.6 KB: [k][w(swizzled 16B slots)][ij]

    // stage kern row (n,h): 6400 floats, coalesced float4 copy, swizzled slots
    {
        const float4* src = (const float4*)(kern2 + (size_t)(n * 64 + h) * 6400);
        float4* dst = (float4*)ks;
#pragma unroll
        for (int i = 0; i < 7; i++) {
            int idx = tid + i * 256;
            if (idx < 1600) {
                int k = idx >> 6, j = idx & 63;
                dst[(k << 6) + (j ^ ((j >> 3) & 1))] = src[idx];
            }
        }
    }

    // y halo as packed bf16: 4 o x 5 rows x 3 dwords (cols 2wp-2 .. 2wp+3)
    unsigned int yraw[4][5][3];
    {
        const unsigned short* yb = y1b + ((size_t)(n * OC_ + o0 + ol * 4)) * HW_ + (2 * wp - 2);
#pragma unroll
        for (int o = 0; o < 4; o++) {
#pragma unroll
            for (int di = 0; di < 5; di++) {
                int gh  = h - 2 + di;
                int ghc = gh < 0 ? 0 : (gh > H_ - 1 ? H_ - 1 : gh);
                bool rok = (gh >= 0) && (gh < H_);
                const unsigned short* yr = yb + (size_t)o * HW_ + ghc * W_;
                yraw[o][di][0] = (rok && wp > 0)  ? *(const unsigned int*)(yr)     : 0u;
                yraw[o][di][1] =  rok             ? *(const unsigned int*)(yr + 2) : 0u;
                yraw[o][di][2] = (rok && wp < 31) ? *(const unsigned int*)(yr + 4) : 0u;
            }
        }
    }
    __syncthreads();

    f32x2 acc[4][2][2];            // [o][ww][ij-pair]
#pragma unroll
    for (int o = 0; o < 4; o++)
#pragma unroll
        for (int w = 0; w < 2; w++)
#pragma unroll
            for (int p = 0; p < 2; p++) acc[o][w][p] = (f32x2)(0.f);

    const char* kb  = (const char*)ks + wp * 32;
    const int   fsw = (wp >> 2) & 1;     // swizzle: swap 16B halves when wp bit2 set
#pragma unroll
    for (int di = 0; di < 5; di++) {
        f32x2 yv[4][3];
#pragma unroll
        for (int o = 0; o < 4; o++)
#pragma unroll
            for (int q = 0; q < 3; q++)
                yv[o][q] = bfp2f(yraw[o][di][q]);
#pragma unroll
        for (int dj = 0; dj < 5; dj++) {
            const int k = di * 5 + dj;
            union { f32x4 v; f32x2 h2[2]; } kw0, kw1;
            kw0.v = *(const f32x4*)(kb + k * 1024 + (fsw << 4));        // kern[k][w0][ij0..3]
            kw1.v = *(const f32x4*)(kb + k * 1024 + 16 - (fsw << 4));   // kern[k][w1][ij0..3]
#pragma unroll
            for (int o = 0; o < 4; o++) {
                f32x2 pa = yv[o][dj >> 1];
                f32x2 pb = yv[o][(dj + 1) >> 1];
                if (dj & 1) {
                    pk_fma_hi(acc[o][0][0], kw0.h2[0], pa);
                    pk_fma_hi(acc[o][0][1], kw0.h2[1], pa);
                    pk_fma_lo(acc[o][1][0], kw1.h2[0], pb);
                    pk_fma_lo(acc[o][1][1], kw1.h2[1], pb);
                } else {
                    pk_fma_lo(acc[o][0][0], kw0.h2[0], pa);
                    pk_fma_lo(acc[o][0][1], kw0.h2[1], pa);
                    pk_fma_hi(acc[o][1][0], kw1.h2[0], pb);
                    pk_fma_hi(acc[o][1][1], kw1.h2[1], pb);
                }
            }
        }
    }

#pragma unroll
    for (int o = 0; o < 4; o++) {
        int oo = o0 + ol * 4 + o;
        float bias = bo[oo];
        float* op = out + (((size_t)(n * OC_ + oo)) * H2_ + 2 * h) * W2_ + 4 * wp;
        float4 r0 = make_float4(acc[o][0][0].x + bias, acc[o][0][0].y + bias,
                                acc[o][1][0].x + bias, acc[o][1][0].y + bias);
        float4 r1 = make_float4(acc[o][0][1].x + bias, acc[o][0][1].y + bias,
                                acc[o][1][1].x + bias, acc[o][1][1].y + bias);
        *(float4*)op         = r0;
        *(float4*)(op + W2_) = r1;
    }
}

extern "C" void kernel_launch(void* const* d_in, const int* in_sizes, int n_in,
                              void* d_out, int out_size, void* d_ws, size_t ws_size,
                              hipStream_t stream) {
    const float* x  = (const float*)d_in[0];
    const float* Wd = (const float*)d_in[1];
    const float* bd = (const float*)d_in[2];
    const float* We = (const float*)d_in[3];
    const float* be = (const float*)d_in[4];
    const float* Wo = (const float*)d_in[5];
    const float* bo = (const float*)d_in[6];
    float* out = (float*)d_out;

    // workspace (bytes), total 17,186,816:
    //   y1b   [0,          8,388,608)   bf16 4x256x4096
    //   kern2 [8,388,608,  14,942,208)  fp32 4x64x25x64x4  (layout [n][h][k][w][ij])
    //         (Wcat bf16 163,840 B aliases its head; dead before k_encsm writes)
    //   t2    [14,942,208, 17,039,360)  bf16 4x4096x64
    //   Web   [17,039,360, 17,186,816)  bf16 9x128x64
    char* wsb = (char*)d_ws;
    unsigned short* y1b  = (unsigned short*)wsb;
    float*          kern2= (float*)(wsb + 8388608);
    unsigned short* Wcat = (unsigned short*)(wsb + 8388608);
    unsigned short* t2   = (unsigned short*)(wsb + 14942208);
    unsigned short* Web  = (unsigned short*)(wsb + 17039360);

    k_prep  <<<608,  256, 0, stream>>>(Wo, Wd, We, Wcat, Web);
    k_gemm  <<<512,  640, 0, stream>>>(x, Wcat, bd, y1b, t2);
    k_encsm <<<512,  256, 0, stream>>>(t2, Web, be, kern2);
    k_reasm <<<2048, 256, 0, stream>>>(y1b, kern2, bo, out);
}